// Round 19
// baseline (834.709 us; speedup 1.0000x reference)
//
#include <hip/hip_runtime.h>
#include <hip/hip_bf16.h>

typedef __attribute__((ext_vector_type(4))) float f32x4;
typedef __attribute__((ext_vector_type(8))) short short8;
typedef __attribute__((ext_vector_type(4))) unsigned int u32x4;
typedef __attribute__((ext_vector_type(4))) unsigned short u16x4;

static __device__ __forceinline__ unsigned short f2bf(float f){
  unsigned u = __builtin_bit_cast(unsigned, f);
  u += 0x7FFFu + ((u >> 16) & 1u);
  return (unsigned short)(u >> 16);
}
static __device__ __forceinline__ float bf2f(unsigned short b){
  return __builtin_bit_cast(float, ((unsigned)b) << 16);
}
// float -> OCP e4m3fn (software; one-time cvt kernel + fallback)
static __device__ __forceinline__ unsigned char f2e4m3(float x){
  unsigned u = __builtin_bit_cast(unsigned, x);
  unsigned s = (u >> 24) & 0x80u;
  float ax = __builtin_fabsf(x);
  if (ax < 0.015625f) {
    int q = (int)(ax * 512.f + 0.5f);
    return (unsigned char)(s | (unsigned)q);
  }
  if (ax > 448.f) return (unsigned char)(s | 0x7Eu);
  unsigned v = __builtin_bit_cast(unsigned, ax);
  v += 0x00080000u + ((v >> 20) & 1u);
  if (__builtin_bit_cast(float, v & 0xFFF00000u) > 448.f)
    return (unsigned char)(s | 0x7Eu);
  unsigned ee = ((v >> 23) & 0xFFu) - 127u + 7u;
  unsigned m = (v >> 20) & 7u;
  return (unsigned char)(s | (ee << 3) | m);
}
static __device__ __forceinline__ unsigned char h2fp8(float hx16){
#if __has_builtin(__builtin_amdgcn_cvt_pk_fp8_f32)
  int pk = __builtin_amdgcn_cvt_pk_fp8_f32(hx16, hx16, 0, false);
  return (unsigned char)(pk & 0xFF);
#else
  return f2e4m3(hx16);
#endif
}
static __device__ __forceinline__ f32x4 mfma16(short8 a, short8 b, f32x4 c){
  return __builtin_amdgcn_mfma_f32_16x16x32_bf16(a, b, c, 0, 0, 0);
}
static __device__ __forceinline__ f32x4 mfma8(long a, long b, f32x4 c){
  return __builtin_amdgcn_mfma_f32_16x16x32_fp8_fp8(a, b, c, 0, 0, 0);
}
static __device__ __forceinline__ float rcpf(float x){ return __builtin_amdgcn_rcpf(x); }
static __device__ __forceinline__ float sigf(float x){ return rcpf(1.f + __expf(-x)); }
static __device__ __forceinline__ float tanhfast(float x){
  float e = __expf(2.f*x);
  return (e - 1.f) * rcpf(e + 1.f);
}

// ---------------------------------------------------------------------------
// fp32 -> bf16 weight conversion (head_W + 7 small matrices of 196608 elems)
// ---------------------------------------------------------------------------
__global__ __launch_bounds__(256) void k_cvt(
    const float* __restrict__ sh, unsigned short* __restrict__ dh,
    const float* __restrict__ s0, const float* __restrict__ s1,
    const float* __restrict__ s2, const float* __restrict__ s3,
    const float* __restrict__ s4, const float* __restrict__ s5,
    const float* __restrict__ s6,
    unsigned short* __restrict__ d0, unsigned short* __restrict__ d1,
    unsigned short* __restrict__ d2, unsigned short* __restrict__ d3,
    unsigned short* __restrict__ d4, unsigned short* __restrict__ d5,
    unsigned short* __restrict__ d6)
{
  const long NH4 = 2048000;
  const long NS4 = 49152;
  const long total = NH4 + 7*NS4;
  for (long idx = (long)blockIdx.x*blockDim.x + threadIdx.x; idx < total;
       idx += (long)gridDim.x*blockDim.x) {
    const float* s; unsigned short* d; long off;
    if (idx < NH4) { s = sh; d = dh; off = idx; }
    else {
      long r = idx - NH4; int mat = (int)(r / NS4); off = r - (long)mat*NS4;
      switch (mat) {
        case 0: s=s0; d=d0; break;  case 1: s=s1; d=d1; break;
        case 2: s=s2; d=d2; break;  case 3: s=s3; d=d3; break;
        case 4: s=s4; d=d4; break;  case 5: s=s5; d=d5; break;
        default: s=s6; d=d6; break;
      }
    }
    f32x4 v = ((const f32x4*)s)[off];
    u16x4 o2;
    o2[0]=f2bf(v[0]); o2[1]=f2bf(v[1]); o2[2]=f2bf(v[2]); o2[3]=f2bf(v[3]);
    ((u16x4*)d)[off] = o2;
  }
}

// ---------------------------------------------------------------------------
// Whh split conversion (layouts as R17/R18):
//   r gate -> bf16 FRAG-MAJOR: elem off (w*8+kb)*512 + lane*8
//   z/n    -> fp8 e4m3 x16: byte off ((w*2+g)*8+kb)*512 + lane*8
// ---------------------------------------------------------------------------
__global__ __launch_bounds__(256) void k_cvtw(
    const float* __restrict__ s0, const float* __restrict__ s1,
    const float* __restrict__ s2,
    unsigned short* __restrict__ r0, unsigned short* __restrict__ r1,
    unsigned short* __restrict__ r2,
    unsigned char* __restrict__ z0, unsigned char* __restrict__ z1,
    unsigned char* __restrict__ z2)
{
  int idx = blockIdx.x*256 + threadIdx.x;     // 3 mats x 24576 work items
  if (idx >= 3*24576) return;
  int mat = idx / 24576, c = idx % 24576;
  const float* s = (mat==0) ? s0 : (mat==1 ? s1 : s2);
  if (c < 8192) {                             // r chunk: 16B bf16
    unsigned short* d = (mat==0) ? r0 : (mat==1 ? r1 : r2);
    int w = c >> 9, rest = c & 511;
    int kb = rest >> 6, lane = rest & 63;
    int row = w*16 + (lane & 15);
    int k0  = kb*32 + (lane >> 4)*8;
    const float* sp = s + (long)row*256 + k0;
    f32x4 a = *(const f32x4*)sp;
    f32x4 b = *(const f32x4*)(sp + 4);
    short8 o;
    o[0]=(short)f2bf(a[0]); o[1]=(short)f2bf(a[1]);
    o[2]=(short)f2bf(a[2]); o[3]=(short)f2bf(a[3]);
    o[4]=(short)f2bf(b[0]); o[5]=(short)f2bf(b[1]);
    o[6]=(short)f2bf(b[2]); o[7]=(short)f2bf(b[3]);
    *(short8*)(d + (long)c*8) = o;
  } else {                                    // zn chunk: 8B fp8 x16
    int c2 = c - 8192;                        // 16384 chunks
    unsigned char* d = (mat==0) ? z0 : (mat==1 ? z1 : z2);
    int w = c2 >> 10, rest = c2 & 1023;
    int g = rest >> 9, r_ = rest & 511;
    int kb = r_ >> 6, lane = r_ & 63;
    int row = (1+g)*256 + w*16 + (lane & 15);
    int k0  = kb*32 + (lane >> 4)*8;
    const float* sp = s + (long)row*256 + k0;
    f32x4 a = *(const f32x4*)sp;
    f32x4 b = *(const f32x4*)(sp + 4);
    unsigned char ob[8];
    ob[0]=f2e4m3(a[0]*16.f); ob[1]=f2e4m3(a[1]*16.f);
    ob[2]=f2e4m3(a[2]*16.f); ob[3]=f2e4m3(a[3]*16.f);
    ob[4]=f2e4m3(b[0]*16.f); ob[5]=f2e4m3(b[1]*16.f);
    ob[6]=f2e4m3(b[2]*16.f); ob[7]=f2e4m3(b[3]*16.f);
    unsigned lo = (unsigned)ob[0] | ((unsigned)ob[1]<<8) |
                  ((unsigned)ob[2]<<16) | ((unsigned)ob[3]<<24);
    unsigned hi = (unsigned)ob[4] | ((unsigned)ob[5]<<8) |
                  ((unsigned)ob[6]<<16) | ((unsigned)ob[7]<<24);
    *(unsigned*)(d + (long)c2*8)     = lo;
    *(unsigned*)(d + (long)c2*8 + 4) = hi;
  }
}

// ---------------------------------------------------------------------------
// Generic MFMA GEMM: out[M][N] = gatherA[M][Ktot] @ W[N][Ktot]^T + bias
// ---------------------------------------------------------------------------
template<int TN, int TS, int EPI>
__global__ __launch_bounds__(256) void k_gemm(
    const float* __restrict__ tabA, int ldA,
    const float* __restrict__ tabB2, int ldB2, int K1,
    const int* __restrict__ ids,
    const unsigned short* __restrict__ W,   // [N][Ktot] bf16
    const float* __restrict__ bias,         // [N]
    int M, int Ktot,
    void* __restrict__ outp, int ldOut)
{
  const int bm = blockIdx.x, bn = blockIdx.y;
  const int tid = threadIdx.x;
  const int lane = tid & 63, w = tid >> 6;
  const int l15 = lane & 15, l4 = lane >> 4;

  const int r_g = bm*64 + w*16 + l15;
  const int r_c = (r_g < M) ? r_g : (M-1);
  long row_src;
  if (ids) { int ii = (r_c / TN) * TS + (r_c % TN); row_src = ids[ii]; }
  else row_src = r_c;

  const int kchunk = l4 * 8;
  const int ncol0 = bn*128 + l15;

  f32x4 acc[8];
  #pragma unroll
  for (int i=0;i<8;i++){ f32x4 z4 = {0.f,0.f,0.f,0.f}; acc[i]=z4; }

  const int KB = Ktot >> 5;
  for (int kb = 0; kb < KB; ++kb) {
    int k = kb*32 + kchunk;
    const float* ap;
    if (tabB2 && k >= K1) ap = tabB2 + row_src*(long)ldB2 + (k - K1);
    else                  ap = tabA  + row_src*(long)ldA  + k;
    f32x4 a0 = *(const f32x4*)ap;
    f32x4 a1 = *(const f32x4*)(ap + 4);
    short8 afr;
    afr[0]=(short)f2bf(a0[0]); afr[1]=(short)f2bf(a0[1]);
    afr[2]=(short)f2bf(a0[2]); afr[3]=(short)f2bf(a0[3]);
    afr[4]=(short)f2bf(a1[0]); afr[5]=(short)f2bf(a1[1]);
    afr[6]=(short)f2bf(a1[2]); afr[7]=(short)f2bf(a1[3]);
    #pragma unroll
    for (int ct=0; ct<8; ++ct) {
      int n = ncol0 + ct*16;
      short8 bfr = *(const short8*)(W + (long)n*Ktot + k);
      acc[ct] = mfma16(afr, bfr, acc[ct]);
    }
  }

  #pragma unroll
  for (int ct=0; ct<8; ++ct) {
    int n = ncol0 + ct*16;
    float bv = bias[n];
    #pragma unroll
    for (int q=0; q<4; ++q) {
      int rr = bm*64 + w*16 + l4*4 + q;
      if (rr < M) {
        float v = acc[ct][q] + bv;
        if (EPI == 1) ((float*)outp)[(long)rr*ldOut + n] = tanhfast(v);
        else ((unsigned short*)outp)[(long)rr*ldOut + n] = f2bf(v);
      }
    }
  }
}

// ---------------------------------------------------------------------------
// GRU recurrence, ROW-SPLIT (4 rows/block) + IN-LANE GATES + 1 BARRIER/STEP.
//   R18 (row-split, 2 barriers, hg round-trip, z/n in LDS) = 4270 cy/step.
//   This round:
//   - gates computed IN the C-holding lanes (l4==0): MFMA C layout puts
//     rows 0-3 exactly there -> no hg LDS buffer, ONE barrier/step.
//   - z/n fp8 weights in 32 VGPRs/wave (16 longs) + r bf16 in 32 VGPRs:
//     64 weight VGPRs, projected total ~115 < 128 cap -> no Wzn LDS reads
//     (-128KB/step of the 320KB/step LDS floor). LDS drops to ~7.2KB.
//   h state exact f32 in C-lane registers. Numerics identical to R18.
// ---------------------------------------------------------------------------
__global__ __launch_bounds__(1024, 1) void k_gru(
    const unsigned short* __restrict__ WR,   // bf16 r frag-major (k_cvtw)
    const unsigned char*  __restrict__ WZN,  // fp8 z/n frag-major (k_cvtw)
    const float* __restrict__ bhh,           // [768]
    const unsigned short* __restrict__ xg,   // [(grow*T+t)][768] bf16 (bih inc.)
    const int* __restrict__ mask,            // [(grow*T+t)] or null
    const unsigned short* __restrict__ h0bf, // [16][256] bf16 GLOBAL rows, or null
    float* __restrict__ hNf,                 // [grow][256] f32 or null
    unsigned short* __restrict__ hNbf,       // [16][256] bf16 GLOBAL rows, or null
    unsigned short* __restrict__ outs,       // [(grow*T+t)][256] bf16 or null
    int T)
{
  __shared__ unsigned short hbz[9*264];      // bf16 h: rows 0-3=p0, 4-7=p1, 8=zero
  __shared__ unsigned char  h8z[9*264];      // fp8 h (x16), same row plan

  const int tid = threadIdx.x;
  const int w = tid >> 6, lane = tid & 63;
  const int l15 = lane & 15, l4 = lane >> 4;
  const int rowbase = blockIdx.x * 4;
  const int u = w*16 + l15;                  // unit (valid for C-lanes l4==0)
  const bool clane = (l4 == 0);

  // ---- weights -> registers: r bf16 (32 VGPR) + z/n fp8 (32 VGPR) ----
  short8 Br[8];
  long Bz8[8], Bn8[8];
  #pragma unroll
  for (int kb=0; kb<8; ++kb) {
    Br[kb]  = *(const short8*)(WR + ((long)(w*8+kb)*512) + lane*8);
    Bz8[kb] = *(const long*)(WZN + ((long)((w*2+0)*8+kb)*512) + lane*8);
    Bn8[kb] = *(const long*)(WZN + ((long)((w*2+1)*8+kb)*512) + lane*8);
  }

  const float b_r = bhh[u], b_z = bhh[256+u], b_n = bhh[512+u];

  // A-read offsets (parity-selected; tile rows >=4 alias zero-row 8)
  const int arow0 = (l15 < 4) ? l15     : 8;
  const int arow1 = (l15 < 4) ? 4 + l15 : 8;
  const int hbO0 = (arow0*264 + l4*8)*2;
  const int hbO1 = (arow1*264 + l4*8)*2;
  const int h8O0 =  arow0*264 + l4*8;
  const int h8O1 =  arow1*264 + l4*8;

  // ---- init: zero row 8; h0 -> rows 0-3 (C-lanes); exact h in f32 regs ----
  if (tid < 264) { hbz[8*264 + tid] = 0; h8z[8*264 + tid] = 0; }
  float h[4] = {0.f, 0.f, 0.f, 0.f};
  if (clane) {
    #pragma unroll
    for (int q=0; q<4; ++q) {
      float hv = h0bf ? bf2f(h0bf[(rowbase+q)*256 + u]) : 0.f;
      h[q] = hv;
      hbz[q*264 + u] = f2bf(hv);
      h8z[q*264 + u] = h2fp8(hv * 16.f);
    }
  }
  __syncthreads();

  const float inv256 = 0.00390625f;

  for (int t=0; t<T; ++t) {
    const int p = t & 1;

    // ---- xg prefetch (C-lanes; hides under MFMA phase) ----
    unsigned short xr_[4], xz_[4], xn_[4];
    int mok[4];
    if (clane) {
      #pragma unroll
      for (int q=0; q<4; ++q) {
        long xrow = (long)(rowbase + q)*T + t;
        mok[q] = mask ? mask[xrow] : 1;
        const unsigned short* xp = xg + xrow*768;
        xr_[q] = xp[u]; xz_[q] = xp[256+u]; xn_[q] = xp[512+u];
      }
    }

    // ---- MFMA: 16 units x 3 gates per wave; all weights in registers ----
    const int hbO = p ? hbO1 : hbO0;
    const int h8O = p ? h8O1 : h8O0;
    f32x4 aR={0.f,0.f,0.f,0.f}, aZ={0.f,0.f,0.f,0.f}, aN={0.f,0.f,0.f,0.f};
    #pragma unroll
    for (int kb=0; kb<8; ++kb) {
      short8 af = *(const short8*)((const char*)hbz + hbO + kb*64);
      long   a8 = *(const long*)((const char*)h8z + h8O + kb*32);
      aR = mfma16(af, Br[kb], aR);
      aZ = mfma8(a8, Bz8[kb], aZ);
      aN = mfma8(a8, Bn8[kb], aN);
    }

    // ---- gates IN the C-lanes (C rows 0-3 live exactly here) ----
    if (clane) {
      const int wbase = (p^1)*4;
      #pragma unroll
      for (int q=0; q<4; ++q) {
        float rr = sigf(bf2f(xr_[q]) + aR[q] + b_r);
        float zz = sigf(bf2f(xz_[q]) + aZ[q]*inv256 + b_z);
        float nn = tanhfast(bf2f(xn_[q]) + rr*(aN[q]*inv256 + b_n));
        float hv = nn + zz*(h[q] - nn);
        if (!mok[q]) hv = h[q];
        h[q] = hv;
        const unsigned short hbv = f2bf(hv);
        hbz[(wbase+q)*264 + u] = hbv;
        h8z[(wbase+q)*264 + u] = h2fp8(hv * 16.f);
        if (outs) {
          long xrow = (long)(rowbase + q)*T + t;
          outs[xrow*256 + u] = hbv;
        }
      }
    }
    __syncthreads();
  }

  if (clane && (hNf || hNbf)) {
    #pragma unroll
    for (int q=0; q<4; ++q) {
      if (hNf)  hNf[(long)(rowbase+q)*256 + u] = h[q];
      if (hNbf) hNbf[(rowbase+q)*256 + u] = f2bf(h[q]);
    }
  }
}

// ---------------------------------------------------------------------------
// Memory scan: per batch b (block, 1 wave): 32 steps of attention-write memory.
// ---------------------------------------------------------------------------
__global__ __launch_bounds__(64) void k_mem(
    const float* __restrict__ z,         // [512][256] rows b*32+t
    const float* __restrict__ mem_init,  // [16][256]
    float* __restrict__ z2)              // [512][256]
{
  const int b = blockIdx.x;
  const int lane = threadIdx.x;
  float mem[16][4];
  #pragma unroll
  for (int m=0; m<16; ++m) {
    f32x4 v = *(const f32x4*)(mem_init + m*256 + lane*4);
    mem[m][0]=v[0]; mem[m][1]=v[1]; mem[m][2]=v[2]; mem[m][3]=v[3];
  }
  for (int t=0; t<32; ++t) {
    f32x4 q = *(const f32x4*)(z + ((long)b*32 + t)*256 + lane*4);
    float s[16];
    #pragma unroll
    for (int m=0; m<16; ++m)
      s[m] = mem[m][0]*q[0] + mem[m][1]*q[1] + mem[m][2]*q[2] + mem[m][3]*q[3];
    #pragma unroll
    for (int st=1; st<64; st<<=1) {
      #pragma unroll
      for (int m=0; m<16; ++m) s[m] += __shfl_xor(s[m], st, 64);
    }
    float mx = -1e30f;
    #pragma unroll
    for (int m=0; m<16; ++m) { s[m] *= 0.0625f; mx = fmaxf(mx, s[m]); }
    float sum = 0.f;
    #pragma unroll
    for (int m=0; m<16; ++m) { s[m] = __expf(s[m]-mx); sum += s[m]; }
    float inv = rcpf(sum);
    f32x4 ro = {0.f,0.f,0.f,0.f};
    #pragma unroll
    for (int m=0; m<16; ++m) {
      float wm = s[m]*inv;
      #pragma unroll
      for (int c=0; c<4; ++c) {
        ro[c] += wm * mem[m][c];
        mem[m][c] += wm * (q[c] - mem[m][c]);
      }
    }
    f32x4 o = q + ro;
    *(f32x4*)(z2 + ((long)b*32 + t)*256 + lane*4) = o;
  }
}

// ---------------------------------------------------------------------------
// Head GEMM: out[2032][32000] = A[2032][256]bf16 @ Bw[32000][256]^T + bias
// ---------------------------------------------------------------------------
__global__ __launch_bounds__(256) void k_head(
    const unsigned short* __restrict__ A,    // [2048][256] bf16 (padded)
    const unsigned short* __restrict__ Bw,   // [32000][256] bf16
    const float* __restrict__ bias,          // [32000]
    float* __restrict__ out,                 // [2032][32000]
    int M)
{
  __shared__ unsigned short Bs[32768];       // 64 KB
  const int bid = blockIdx.x;
  const int mt = bid % 16, nt = bid / 16;
  const int tid = threadIdx.x;
  const int lane = tid & 63, w = tid >> 6;
  const int l15 = lane & 15, l4 = lane >> 4;

  const long nbase = (long)nt * 128;
  #pragma unroll
  for (int it=0; it<16; ++it) {
    int idx = it*256 + tid;
    int rr = idx >> 5;
    int ch = idx & 31;
    int sch = ch ^ (rr & 7);
    u32x4 v = *(const u32x4*)(Bw + (nbase+rr)*256 + sch*8);
    *(u32x4*)&Bs[(long)idx*8] = v;
  }
  __syncthreads();

  const int m0 = mt*128 + w*32;
  const int arow0 = m0 + l15, arow1 = arow0 + 16;
  const int kc = l4 * 8;

  f32x4 acc[2][8];
  #pragma unroll
  for (int rt=0; rt<2; ++rt)
    #pragma unroll
    for (int ct=0; ct<8; ++ct){ f32x4 z4={0.f,0.f,0.f,0.f}; acc[rt][ct]=z4; }

  #pragma unroll
  for (int kb=0; kb<8; ++kb) {
    short8 a0 = *(const short8*)(A + (long)arow0*256 + kb*32 + kc);
    short8 a1 = *(const short8*)(A + (long)arow1*256 + kb*32 + kc);
    int c = kb*4 + l4;
    #pragma unroll
    for (int ct=0; ct<8; ++ct) {
      int n_local = ct*16 + l15;
      int sc = c ^ (n_local & 7);
      short8 bf = *(const short8*)&Bs[((long)n_local*32 + sc)*8];
      acc[0][ct] = mfma16(a0, bf, acc[0][ct]);
      acc[1][ct] = mfma16(a1, bf, acc[1][ct]);
    }
  }

  #pragma unroll
  for (int ct=0; ct<8; ++ct) {
    int n_g = nt*128 + ct*16 + l15;
    float bv = bias[n_g];
    #pragma unroll
    for (int rt=0; rt<2; ++rt) {
      #pragma unroll
      for (int q=0; q<4; ++q) {
        int r_g = m0 + rt*16 + l4*4 + q;
        if (r_g < M) out[(long)r_g*32000 + n_g] = acc[rt][ct][q] + bv;
      }
    }
  }
}

// ---------------------------------------------------------------------------
extern "C" void kernel_launch(void* const* d_in, const int* in_sizes, int n_in,
                              void* d_out, int out_size, void* d_ws, size_t ws_size,
                              hipStream_t stream)
{
  (void)in_sizes; (void)n_in; (void)out_size; (void)ws_size;
  const int*   ctx_ids  = (const int*)  d_in[0];
  const int*   ctx_mask = (const int*)  d_in[1];
  const float* img      = (const float*)d_in[2];
  const int*   tgt_ids  = (const int*)  d_in[3];
  const float* emb_text = (const float*)d_in[4];
  const float* Wih_t    = (const float*)d_in[5];
  const float* Whh_t    = (const float*)d_in[6];
  const float* bih_t    = (const float*)d_in[7];
  const float* bhh_t    = (const float*)d_in[8];
  const float* fuse_W   = (const float*)d_in[9];
  const float* fuse_b   = (const float*)d_in[10];
  const float* mem_init = (const float*)d_in[11];
  const float* Wih_c    = (const float*)d_in[12];
  const float* Whh_c    = (const float*)d_in[13];
  const float* bih_c    = (const float*)d_in[14];
  const float* bhh_c    = (const float*)d_in[15];
  const float* tok_emb  = (const float*)d_in[16];
  const float* Wih_d    = (const float*)d_in[17];
  const float* Whh_d    = (const float*)d_in[18];
  const float* bih_d    = (const float*)d_in[19];
  const float* bhh_d    = (const float*)d_in[20];
  const float* head_W   = (const float*)d_in[21];
  const float* head_b   = (const float*)d_in[22];
  float* out = (float*)d_out;
  char* ws = (char*)d_ws;

  size_t o = 0;
  auto alloc = [&](size_t bytes){ size_t r = o; o += (bytes + 255) & ~(size_t)255; return r; };
  unsigned short* wWih_t = (unsigned short*)(ws + alloc(768*256*2));
  unsigned short* wWhh_t = (unsigned short*)(ws + alloc(768*256*2));
  unsigned short* wWih_c = (unsigned short*)(ws + alloc(768*256*2));
  unsigned short* wWhh_c = (unsigned short*)(ws + alloc(768*256*2));
  unsigned short* wWih_d = (unsigned short*)(ws + alloc(768*256*2));
  unsigned short* wWhh_d = (unsigned short*)(ws + alloc(768*256*2));
  unsigned short* wFuse  = (unsigned short*)(ws + alloc(256*768*2));
  unsigned short* wR_t   = (unsigned short*)(ws + alloc(65536*2));
  unsigned short* wR_c   = (unsigned short*)(ws + alloc(65536*2));
  unsigned short* wR_d   = (unsigned short*)(ws + alloc(65536*2));
  unsigned char*  wZN_t  = (unsigned char*)(ws + alloc(131072));
  unsigned char*  wZN_c  = (unsigned char*)(ws + alloc(131072));
  unsigned char*  wZN_d  = (unsigned char*)(ws + alloc(131072));
  unsigned short* wHead  = (unsigned short*)(ws + alloc((size_t)32000*256*2));
  unsigned short* xg_t   = (unsigned short*)(ws + alloc((size_t)16384*768*2));
  unsigned short* xg_c   = (unsigned short*)(ws + alloc((size_t)512*768*2));
  unsigned short* xg_d   = (unsigned short*)(ws + alloc((size_t)2032*768*2));
  float*          tvec   = (float*)(ws + alloc((size_t)512*256*4));
  float*          zbuf   = (float*)(ws + alloc((size_t)512*256*4));
  float*          z2buf  = (float*)(ws + alloc((size_t)512*256*4));
  unsigned short* outsb  = (unsigned short*)(ws + alloc((size_t)2048*256*2));
  unsigned short* hbdec  = (unsigned short*)(ws + alloc((size_t)16*256*2));

  // 0) weights -> bf16 (all) + split r/zn conversion (Whh x3)
  k_cvt<<<2048, 256, 0, stream>>>(head_W, wHead,
      Wih_t, Whh_t, Wih_c, Whh_c, Wih_d, Whh_d, fuse_W,
      wWih_t, wWhh_t, wWih_c, wWhh_c, wWih_d, wWhh_d, wFuse);
  k_cvtw<<<288, 256, 0, stream>>>(Whh_t, Whh_c, Whh_d,
                                  wR_t, wR_c, wR_d, wZN_t, wZN_c, wZN_d);

  // 1) xg for ctx text GRU: rows = (b*K+k)*L + l = 16384
  k_gemm<32,32,0><<<dim3(256,6), 256, 0, stream>>>(
      emb_text, 256, nullptr, 0, 256, ctx_ids, wWih_t, bih_t, 16384, 256, xg_t, 768);

  // 1b) xg for decoder (independent): rows = b*127 + t = 2032
  k_gemm<127,128,0><<<dim3(32,6), 256, 0, stream>>>(
      tok_emb, 256, nullptr, 0, 256, tgt_ids, wWih_d, bih_d, 2032, 256, xg_d, 768);

  // 2) ctx text GRU (masked), 512 rows / 4 = 128 blocks -> tvec (f32)
  k_gru<<<128, 1024, 0, stream>>>(wR_t, wZN_t, bhh_t, xg_t, ctx_mask,
                                  nullptr, tvec, nullptr, nullptr, 32);

  // 3) fuse: z = tanh([tvec|img] @ fuse_W^T + fuse_b), 512x256
  k_gemm<1,1,1><<<dim3(8,2), 256, 0, stream>>>(
      tvec, 256, img, 512, 256, nullptr, wFuse, fuse_b, 512, 768, zbuf, 256);

  // 4) memory scan -> z2
  k_mem<<<16, 64, 0, stream>>>(zbuf, mem_init, z2buf);

  // 5) xg for ctx GRU2 from z2 (rows b*32+t = 512)
  k_gemm<1,1,0><<<dim3(8,6), 256, 0, stream>>>(
      z2buf, 256, nullptr, 0, 256, nullptr, wWih_c, bih_c, 512, 256, xg_c, 768);

  // 6) ctx GRU2: 16 rows / 4 = 4 blocks -> h0 (bf16, global rows)
  k_gru<<<4, 1024, 0, stream>>>(wR_c, wZN_c, bhh_c, xg_c, nullptr,
                                nullptr, nullptr, hbdec, nullptr, 32);

  // 7) decoder GRU: 16 rows / 4 = 4 blocks, h0 preloaded -> outs bf16
  k_gru<<<4, 1024, 0, stream>>>(wR_d, wZN_d, bhh_d, xg_d, nullptr,
                                hbdec, nullptr, nullptr, outsb, 127);

  // 8) head: logits
  k_head<<<4000, 256, 0, stream>>>(outsb, wHead, head_b, out, 2032);
}

// Round 20
// 670.793 us; speedup vs baseline: 1.2444x; 1.2444x over previous
//
#include <hip/hip_runtime.h>
#include <hip/hip_bf16.h>

typedef __attribute__((ext_vector_type(4))) float f32x4;
typedef __attribute__((ext_vector_type(8))) short short8;
typedef __attribute__((ext_vector_type(4))) unsigned int u32x4;
typedef __attribute__((ext_vector_type(4))) unsigned short u16x4;

static __device__ __forceinline__ unsigned short f2bf(float f){
  unsigned u = __builtin_bit_cast(unsigned, f);
  u += 0x7FFFu + ((u >> 16) & 1u);
  return (unsigned short)(u >> 16);
}
static __device__ __forceinline__ float bf2f(unsigned short b){
  return __builtin_bit_cast(float, ((unsigned)b) << 16);
}
// float -> OCP e4m3fn (software; one-time cvt kernel + fallback)
static __device__ __forceinline__ unsigned char f2e4m3(float x){
  unsigned u = __builtin_bit_cast(unsigned, x);
  unsigned s = (u >> 24) & 0x80u;
  float ax = __builtin_fabsf(x);
  if (ax < 0.015625f) {
    int q = (int)(ax * 512.f + 0.5f);
    return (unsigned char)(s | (unsigned)q);
  }
  if (ax > 448.f) return (unsigned char)(s | 0x7Eu);
  unsigned v = __builtin_bit_cast(unsigned, ax);
  v += 0x00080000u + ((v >> 20) & 1u);
  if (__builtin_bit_cast(float, v & 0xFFF00000u) > 448.f)
    return (unsigned char)(s | 0x7Eu);
  unsigned ee = ((v >> 23) & 0xFFu) - 127u + 7u;
  unsigned m = (v >> 20) & 7u;
  return (unsigned char)(s | (ee << 3) | m);
}
static __device__ __forceinline__ unsigned char h2fp8(float hx16){
#if __has_builtin(__builtin_amdgcn_cvt_pk_fp8_f32)
  int pk = __builtin_amdgcn_cvt_pk_fp8_f32(hx16, hx16, 0, false);
  return (unsigned char)(pk & 0xFF);
#else
  return f2e4m3(hx16);
#endif
}
static __device__ __forceinline__ f32x4 mfma16(short8 a, short8 b, f32x4 c){
  return __builtin_amdgcn_mfma_f32_16x16x32_bf16(a, b, c, 0, 0, 0);
}
static __device__ __forceinline__ f32x4 mfma8(long a, long b, f32x4 c){
  return __builtin_amdgcn_mfma_f32_16x16x32_fp8_fp8(a, b, c, 0, 0, 0);
}
static __device__ __forceinline__ float rcpf(float x){ return __builtin_amdgcn_rcpf(x); }
static __device__ __forceinline__ float sigf(float x){ return rcpf(1.f + __expf(-x)); }
static __device__ __forceinline__ float tanhfast(float x){
  float e = __expf(2.f*x);
  return (e - 1.f) * rcpf(e + 1.f);
}
// spread C-fragment: lane (l4,l15) takes component l4 of src-lane l15's vec
static __device__ __forceinline__ float spread4(f32x4 v, int l15, int l4){
  float x0 = __shfl(v[0], l15, 64);
  float x1 = __shfl(v[1], l15, 64);
  float x2 = __shfl(v[2], l15, 64);
  float x3 = __shfl(v[3], l15, 64);
  float s01 = (l4 & 1) ? x1 : x0;
  float s23 = (l4 & 1) ? x3 : x2;
  return (l4 & 2) ? s23 : s01;
}

// ---------------------------------------------------------------------------
// fp32 -> bf16 weight conversion (head_W + 7 small matrices of 196608 elems)
// ---------------------------------------------------------------------------
__global__ __launch_bounds__(256) void k_cvt(
    const float* __restrict__ sh, unsigned short* __restrict__ dh,
    const float* __restrict__ s0, const float* __restrict__ s1,
    const float* __restrict__ s2, const float* __restrict__ s3,
    const float* __restrict__ s4, const float* __restrict__ s5,
    const float* __restrict__ s6,
    unsigned short* __restrict__ d0, unsigned short* __restrict__ d1,
    unsigned short* __restrict__ d2, unsigned short* __restrict__ d3,
    unsigned short* __restrict__ d4, unsigned short* __restrict__ d5,
    unsigned short* __restrict__ d6)
{
  const long NH4 = 2048000;
  const long NS4 = 49152;
  const long total = NH4 + 7*NS4;
  for (long idx = (long)blockIdx.x*blockDim.x + threadIdx.x; idx < total;
       idx += (long)gridDim.x*blockDim.x) {
    const float* s; unsigned short* d; long off;
    if (idx < NH4) { s = sh; d = dh; off = idx; }
    else {
      long r = idx - NH4; int mat = (int)(r / NS4); off = r - (long)mat*NS4;
      switch (mat) {
        case 0: s=s0; d=d0; break;  case 1: s=s1; d=d1; break;
        case 2: s=s2; d=d2; break;  case 3: s=s3; d=d3; break;
        case 4: s=s4; d=d4; break;  case 5: s=s5; d=d5; break;
        default: s=s6; d=d6; break;
      }
    }
    f32x4 v = ((const f32x4*)s)[off];
    u16x4 o2;
    o2[0]=f2bf(v[0]); o2[1]=f2bf(v[1]); o2[2]=f2bf(v[2]); o2[3]=f2bf(v[3]);
    ((u16x4*)d)[off] = o2;
  }
}

// ---------------------------------------------------------------------------
// Whh split conversion (layouts as R17-R19):
//   r gate -> bf16 FRAG-MAJOR: elem off (w*8+kb)*512 + lane*8
//   z/n    -> fp8 e4m3 x16: byte off ((w*2+g)*8+kb)*512 + lane*8
// ---------------------------------------------------------------------------
__global__ __launch_bounds__(256) void k_cvtw(
    const float* __restrict__ s0, const float* __restrict__ s1,
    const float* __restrict__ s2,
    unsigned short* __restrict__ r0, unsigned short* __restrict__ r1,
    unsigned short* __restrict__ r2,
    unsigned char* __restrict__ z0, unsigned char* __restrict__ z1,
    unsigned char* __restrict__ z2)
{
  int idx = blockIdx.x*256 + threadIdx.x;     // 3 mats x 24576 work items
  if (idx >= 3*24576) return;
  int mat = idx / 24576, c = idx % 24576;
  const float* s = (mat==0) ? s0 : (mat==1 ? s1 : s2);
  if (c < 8192) {                             // r chunk: 16B bf16
    unsigned short* d = (mat==0) ? r0 : (mat==1 ? r1 : r2);
    int w = c >> 9, rest = c & 511;
    int kb = rest >> 6, lane = rest & 63;
    int row = w*16 + (lane & 15);
    int k0  = kb*32 + (lane >> 4)*8;
    const float* sp = s + (long)row*256 + k0;
    f32x4 a = *(const f32x4*)sp;
    f32x4 b = *(const f32x4*)(sp + 4);
    short8 o;
    o[0]=(short)f2bf(a[0]); o[1]=(short)f2bf(a[1]);
    o[2]=(short)f2bf(a[2]); o[3]=(short)f2bf(a[3]);
    o[4]=(short)f2bf(b[0]); o[5]=(short)f2bf(b[1]);
    o[6]=(short)f2bf(b[2]); o[7]=(short)f2bf(b[3]);
    *(short8*)(d + (long)c*8) = o;
  } else {                                    // zn chunk: 8B fp8 x16
    int c2 = c - 8192;                        // 16384 chunks
    unsigned char* d = (mat==0) ? z0 : (mat==1 ? z1 : z2);
    int w = c2 >> 10, rest = c2 & 1023;
    int g = rest >> 9, r_ = rest & 511;
    int kb = r_ >> 6, lane = r_ & 63;
    int row = (1+g)*256 + w*16 + (lane & 15);
    int k0  = kb*32 + (lane >> 4)*8;
    const float* sp = s + (long)row*256 + k0;
    f32x4 a = *(const f32x4*)sp;
    f32x4 b = *(const f32x4*)(sp + 4);
    unsigned char ob[8];
    ob[0]=f2e4m3(a[0]*16.f); ob[1]=f2e4m3(a[1]*16.f);
    ob[2]=f2e4m3(a[2]*16.f); ob[3]=f2e4m3(a[3]*16.f);
    ob[4]=f2e4m3(b[0]*16.f); ob[5]=f2e4m3(b[1]*16.f);
    ob[6]=f2e4m3(b[2]*16.f); ob[7]=f2e4m3(b[3]*16.f);
    unsigned lo = (unsigned)ob[0] | ((unsigned)ob[1]<<8) |
                  ((unsigned)ob[2]<<16) | ((unsigned)ob[3]<<24);
    unsigned hi = (unsigned)ob[4] | ((unsigned)ob[5]<<8) |
                  ((unsigned)ob[6]<<16) | ((unsigned)ob[7]<<24);
    *(unsigned*)(d + (long)c2*8)     = lo;
    *(unsigned*)(d + (long)c2*8 + 4) = hi;
  }
}

// ---------------------------------------------------------------------------
// Generic MFMA GEMM: out[M][N] = gatherA[M][Ktot] @ W[N][Ktot]^T + bias
// ---------------------------------------------------------------------------
template<int TN, int TS, int EPI>
__global__ __launch_bounds__(256) void k_gemm(
    const float* __restrict__ tabA, int ldA,
    const float* __restrict__ tabB2, int ldB2, int K1,
    const int* __restrict__ ids,
    const unsigned short* __restrict__ W,   // [N][Ktot] bf16
    const float* __restrict__ bias,         // [N]
    int M, int Ktot,
    void* __restrict__ outp, int ldOut)
{
  const int bm = blockIdx.x, bn = blockIdx.y;
  const int tid = threadIdx.x;
  const int lane = tid & 63, w = tid >> 6;
  const int l15 = lane & 15, l4 = lane >> 4;

  const int r_g = bm*64 + w*16 + l15;
  const int r_c = (r_g < M) ? r_g : (M-1);
  long row_src;
  if (ids) { int ii = (r_c / TN) * TS + (r_c % TN); row_src = ids[ii]; }
  else row_src = r_c;

  const int kchunk = l4 * 8;
  const int ncol0 = bn*128 + l15;

  f32x4 acc[8];
  #pragma unroll
  for (int i=0;i<8;i++){ f32x4 z4 = {0.f,0.f,0.f,0.f}; acc[i]=z4; }

  const int KB = Ktot >> 5;
  for (int kb = 0; kb < KB; ++kb) {
    int k = kb*32 + kchunk;
    const float* ap;
    if (tabB2 && k >= K1) ap = tabB2 + row_src*(long)ldB2 + (k - K1);
    else                  ap = tabA  + row_src*(long)ldA  + k;
    f32x4 a0 = *(const f32x4*)ap;
    f32x4 a1 = *(const f32x4*)(ap + 4);
    short8 afr;
    afr[0]=(short)f2bf(a0[0]); afr[1]=(short)f2bf(a0[1]);
    afr[2]=(short)f2bf(a0[2]); afr[3]=(short)f2bf(a0[3]);
    afr[4]=(short)f2bf(a1[0]); afr[5]=(short)f2bf(a1[1]);
    afr[6]=(short)f2bf(a1[2]); afr[7]=(short)f2bf(a1[3]);
    #pragma unroll
    for (int ct=0; ct<8; ++ct) {
      int n = ncol0 + ct*16;
      short8 bfr = *(const short8*)(W + (long)n*Ktot + k);
      acc[ct] = mfma16(afr, bfr, acc[ct]);
    }
  }

  #pragma unroll
  for (int ct=0; ct<8; ++ct) {
    int n = ncol0 + ct*16;
    float bv = bias[n];
    #pragma unroll
    for (int q=0; q<4; ++q) {
      int rr = bm*64 + w*16 + l4*4 + q;
      if (rr < M) {
        float v = acc[ct][q] + bv;
        if (EPI == 1) ((float*)outp)[(long)rr*ldOut + n] = tanhfast(v);
        else ((unsigned short*)outp)[(long)rr*ldOut + n] = f2bf(v);
      }
    }
  }
}

// ---------------------------------------------------------------------------
// GRU recurrence, ROW-SPLIT (4 rows/block) + SHUFFLE-SPREAD GATES.
//   R18: balanced gates via hg LDS round-trip + 2 barriers = 226us decoder.
//   R19: in-lane gates (1 barrier, reg weights) but gate work concentrated
//        in 16/64 lanes -> VALUBusy 0.90, 309us. This round combines both:
//   - MFMA C-fragment spread across the wave by __shfl (lane l4*16+l15
//     takes row l4 of unit l15 from C-lane l15): 12 shuffles + selects
//     replace the hg LDS round-trip AND its barrier.
//   - every lane computes exactly ONE gate triple (4 rows x 16 units =
//     64 lanes); h exact f32 in its owning lane.
//   - weights fully register-resident (r bf16 32 VGPR + z/n fp8 32 VGPR).
//   One barrier/step; LDS = A-operand buffers only (~7KB).
// ---------------------------------------------------------------------------
__global__ __launch_bounds__(1024, 1) void k_gru(
    const unsigned short* __restrict__ WR,   // bf16 r frag-major (k_cvtw)
    const unsigned char*  __restrict__ WZN,  // fp8 z/n frag-major (k_cvtw)
    const float* __restrict__ bhh,           // [768]
    const unsigned short* __restrict__ xg,   // [(grow*T+t)][768] bf16 (bih inc.)
    const int* __restrict__ mask,            // [(grow*T+t)] or null
    const unsigned short* __restrict__ h0bf, // [16][256] bf16 GLOBAL rows, or null
    float* __restrict__ hNf,                 // [grow][256] f32 or null
    unsigned short* __restrict__ hNbf,       // [16][256] bf16 GLOBAL rows, or null
    unsigned short* __restrict__ outs,       // [(grow*T+t)][256] bf16 or null
    int T)
{
  __shared__ unsigned short hbz[9*264];      // bf16 h: rows 0-3=p0, 4-7=p1, 8=zero
  __shared__ unsigned char  h8z[9*264];      // fp8 h (x16), same row plan

  const int tid = threadIdx.x;
  const int w = tid >> 6, lane = tid & 63;
  const int l15 = lane & 15, l4 = lane >> 4;
  const int rowbase = blockIdx.x * 4;
  const int u = w*16 + l15;                  // this lane's unit
  const int gr = l4;                         // this lane's gate row (0..3)

  // ---- weights -> registers: r bf16 (32 VGPR) + z/n fp8 (32 VGPR) ----
  short8 Br[8];
  long Bz8[8], Bn8[8];
  #pragma unroll
  for (int kb=0; kb<8; ++kb) {
    Br[kb]  = *(const short8*)(WR + ((long)(w*8+kb)*512) + lane*8);
    Bz8[kb] = *(const long*)(WZN + ((long)((w*2+0)*8+kb)*512) + lane*8);
    Bn8[kb] = *(const long*)(WZN + ((long)((w*2+1)*8+kb)*512) + lane*8);
  }

  const float b_r = bhh[u], b_z = bhh[256+u], b_n = bhh[512+u];

  // A-read offsets (parity-selected; tile rows >=4 alias zero-row 8)
  const int arow0 = (l15 < 4) ? l15     : 8;
  const int arow1 = (l15 < 4) ? 4 + l15 : 8;
  const int hbO0 = (arow0*264 + l4*8)*2;
  const int hbO1 = (arow1*264 + l4*8)*2;
  const int h8O0 =  arow0*264 + l4*8;
  const int h8O1 =  arow1*264 + l4*8;

  // ---- init: zero row 8; h0 -> rows 0-3; lane owns (row gr, unit u) ----
  if (tid < 264) { hbz[8*264 + tid] = 0; h8z[8*264 + tid] = 0; }
  float h = h0bf ? bf2f(h0bf[(rowbase+gr)*256 + u]) : 0.f;
  hbz[gr*264 + u] = f2bf(h);
  h8z[gr*264 + u] = h2fp8(h * 16.f);
  __syncthreads();

  const float inv256 = 0.00390625f;

  for (int t=0; t<T; ++t) {
    const int p = t & 1;

    // ---- xg prefetch: one triple per lane (hides under MFMA) ----
    const long xrow = (long)(rowbase + gr)*T + t;
    const unsigned short* xp = xg + xrow*768;
    const unsigned short xr_ = xp[u];
    const unsigned short xz_ = xp[256+u];
    const unsigned short xn_ = xp[512+u];
    const int mok = mask ? mask[xrow] : 1;

    // ---- MFMA: 16 units x 3 gates per wave; all weights in registers ----
    const int hbO = p ? hbO1 : hbO0;
    const int h8O = p ? h8O1 : h8O0;
    f32x4 aR={0.f,0.f,0.f,0.f}, aZ={0.f,0.f,0.f,0.f}, aN={0.f,0.f,0.f,0.f};
    #pragma unroll
    for (int kb=0; kb<8; ++kb) {
      short8 af = *(const short8*)((const char*)hbz + hbO + kb*64);
      long   a8 = *(const long*)((const char*)h8z + h8O + kb*32);
      aR = mfma16(af, Br[kb], aR);
      aZ = mfma8(a8, Bz8[kb], aZ);
      aN = mfma8(a8, Bn8[kb], aN);
    }

    // ---- spread C rows across the wave (row gr of unit u -> this lane) ----
    float gR = spread4(aR, l15, l4);
    float gZ = spread4(aZ, l15, l4);
    float gN = spread4(aN, l15, l4);

    // ---- gates: ONE triple per lane, all 64 lanes busy ----
    float rr = sigf(bf2f(xr_) + gR + b_r);
    float zz = sigf(bf2f(xz_) + gZ*inv256 + b_z);
    float nn = tanhfast(bf2f(xn_) + rr*(gN*inv256 + b_n));
    float hv = nn + zz*(h - nn);
    if (!mok) hv = h;
    h = hv;
    const int wrow = (p^1)*4 + gr;
    const unsigned short hbv = f2bf(hv);
    hbz[wrow*264 + u] = hbv;
    h8z[wrow*264 + u] = h2fp8(hv * 16.f);
    if (outs) outs[xrow*256 + u] = hbv;
    __syncthreads();
  }

  if (hNf)  hNf[(long)(rowbase+gr)*256 + u] = h;
  if (hNbf) hNbf[(rowbase+gr)*256 + u] = f2bf(h);
}

// ---------------------------------------------------------------------------
// Memory scan: per batch b (block, 1 wave): 32 steps of attention-write memory.
// ---------------------------------------------------------------------------
__global__ __launch_bounds__(64) void k_mem(
    const float* __restrict__ z,         // [512][256] rows b*32+t
    const float* __restrict__ mem_init,  // [16][256]
    float* __restrict__ z2)              // [512][256]
{
  const int b = blockIdx.x;
  const int lane = threadIdx.x;
  float mem[16][4];
  #pragma unroll
  for (int m=0; m<16; ++m) {
    f32x4 v = *(const f32x4*)(mem_init + m*256 + lane*4);
    mem[m][0]=v[0]; mem[m][1]=v[1]; mem[m][2]=v[2]; mem[m][3]=v[3];
  }
  for (int t=0; t<32; ++t) {
    f32x4 q = *(const f32x4*)(z + ((long)b*32 + t)*256 + lane*4);
    float s[16];
    #pragma unroll
    for (int m=0; m<16; ++m)
      s[m] = mem[m][0]*q[0] + mem[m][1]*q[1] + mem[m][2]*q[2] + mem[m][3]*q[3];
    #pragma unroll
    for (int st=1; st<64; st<<=1) {
      #pragma unroll
      for (int m=0; m<16; ++m) s[m] += __shfl_xor(s[m], st, 64);
    }
    float mx = -1e30f;
    #pragma unroll
    for (int m=0; m<16; ++m) { s[m] *= 0.0625f; mx = fmaxf(mx, s[m]); }
    float sum = 0.f;
    #pragma unroll
    for (int m=0; m<16; ++m) { s[m] = __expf(s[m]-mx); sum += s[m]; }
    float inv = rcpf(sum);
    f32x4 ro = {0.f,0.f,0.f,0.f};
    #pragma unroll
    for (int m=0; m<16; ++m) {
      float wm = s[m]*inv;
      #pragma unroll
      for (int c=0; c<4; ++c) {
        ro[c] += wm * mem[m][c];
        mem[m][c] += wm * (q[c] - mem[m][c]);
      }
    }
    f32x4 o = q + ro;
    *(f32x4*)(z2 + ((long)b*32 + t)*256 + lane*4) = o;
  }
}

// ---------------------------------------------------------------------------
// Head GEMM: out[2032][32000] = A[2032][256]bf16 @ Bw[32000][256]^T + bias
// ---------------------------------------------------------------------------
__global__ __launch_bounds__(256) void k_head(
    const unsigned short* __restrict__ A,    // [2048][256] bf16 (padded)
    const unsigned short* __restrict__ Bw,   // [32000][256] bf16
    const float* __restrict__ bias,          // [32000]
    float* __restrict__ out,                 // [2032][32000]
    int M)
{
  __shared__ unsigned short Bs[32768];       // 64 KB
  const int bid = blockIdx.x;
  const int mt = bid % 16, nt = bid / 16;
  const int tid = threadIdx.x;
  const int lane = tid & 63, w = tid >> 6;
  const int l15 = lane & 15, l4 = lane >> 4;

  const long nbase = (long)nt * 128;
  #pragma unroll
  for (int it=0; it<16; ++it) {
    int idx = it*256 + tid;
    int rr = idx >> 5;
    int ch = idx & 31;
    int sch = ch ^ (rr & 7);
    u32x4 v = *(const u32x4*)(Bw + (nbase+rr)*256 + sch*8);
    *(u32x4*)&Bs[(long)idx*8] = v;
  }
  __syncthreads();

  const int m0 = mt*128 + w*32;
  const int arow0 = m0 + l15, arow1 = arow0 + 16;
  const int kc = l4 * 8;

  f32x4 acc[2][8];
  #pragma unroll
  for (int rt=0; rt<2; ++rt)
    #pragma unroll
    for (int ct=0; ct<8; ++ct){ f32x4 z4={0.f,0.f,0.f,0.f}; acc[rt][ct]=z4; }

  #pragma unroll
  for (int kb=0; kb<8; ++kb) {
    short8 a0 = *(const short8*)(A + (long)arow0*256 + kb*32 + kc);
    short8 a1 = *(const short8*)(A + (long)arow1*256 + kb*32 + kc);
    int c = kb*4 + l4;
    #pragma unroll
    for (int ct=0; ct<8; ++ct) {
      int n_local = ct*16 + l15;
      int sc = c ^ (n_local & 7);
      short8 bf = *(const short8*)&Bs[((long)n_local*32 + sc)*8];
      acc[0][ct] = mfma16(a0, bf, acc[0][ct]);
      acc[1][ct] = mfma16(a1, bf, acc[1][ct]);
    }
  }

  #pragma unroll
  for (int ct=0; ct<8; ++ct) {
    int n_g = nt*128 + ct*16 + l15;
    float bv = bias[n_g];
    #pragma unroll
    for (int rt=0; rt<2; ++rt) {
      #pragma unroll
      for (int q=0; q<4; ++q) {
        int r_g = m0 + rt*16 + l4*4 + q;
        if (r_g < M) out[(long)r_g*32000 + n_g] = acc[rt][ct][q] + bv;
      }
    }
  }
}

// ---------------------------------------------------------------------------
extern "C" void kernel_launch(void* const* d_in, const int* in_sizes, int n_in,
                              void* d_out, int out_size, void* d_ws, size_t ws_size,
                              hipStream_t stream)
{
  (void)in_sizes; (void)n_in; (void)out_size; (void)ws_size;
  const int*   ctx_ids  = (const int*)  d_in[0];
  const int*   ctx_mask = (const int*)  d_in[1];
  const float* img      = (const float*)d_in[2];
  const int*   tgt_ids  = (const int*)  d_in[3];
  const float* emb_text = (const float*)d_in[4];
  const float* Wih_t    = (const float*)d_in[5];
  const float* Whh_t    = (const float*)d_in[6];
  const float* bih_t    = (const float*)d_in[7];
  const float* bhh_t    = (const float*)d_in[8];
  const float* fuse_W   = (const float*)d_in[9];
  const float* fuse_b   = (const float*)d_in[10];
  const float* mem_init = (const float*)d_in[11];
  const float* Wih_c    = (const float*)d_in[12];
  const float* Whh_c    = (const float*)d_in[13];
  const float* bih_c    = (const float*)d_in[14];
  const float* bhh_c    = (const float*)d_in[15];
  const float* tok_emb  = (const float*)d_in[16];
  const float* Wih_d    = (const float*)d_in[17];
  const float* Whh_d    = (const float*)d_in[18];
  const float* bih_d    = (const float*)d_in[19];
  const float* bhh_d    = (const float*)d_in[20];
  const float* head_W   = (const float*)d_in[21];
  const float* head_b   = (const float*)d_in[22];
  float* out = (float*)d_out;
  char* ws = (char*)d_ws;

  size_t o = 0;
  auto alloc = [&](size_t bytes){ size_t r = o; o += (bytes + 255) & ~(size_t)255; return r; };
  unsigned short* wWih_t = (unsigned short*)(ws + alloc(768*256*2));
  unsigned short* wWhh_t = (unsigned short*)(ws + alloc(768*256*2));
  unsigned short* wWih_c = (unsigned short*)(ws + alloc(768*256*2));
  unsigned short* wWhh_c = (unsigned short*)(ws + alloc(768*256*2));
  unsigned short* wWih_d = (unsigned short*)(ws + alloc(768*256*2));
  unsigned short* wWhh_d = (unsigned short*)(ws + alloc(768*256*2));
  unsigned short* wFuse  = (unsigned short*)(ws + alloc(256*768*2));
  unsigned short* wR_t   = (unsigned short*)(ws + alloc(65536*2));
  unsigned short* wR_c   = (unsigned short*)(ws + alloc(65536*2));
  unsigned short* wR_d   = (unsigned short*)(ws + alloc(65536*2));
  unsigned char*  wZN_t  = (unsigned char*)(ws + alloc(131072));
  unsigned char*  wZN_c  = (unsigned char*)(ws + alloc(131072));
  unsigned char*  wZN_d  = (unsigned char*)(ws + alloc(131072));
  unsigned short* wHead  = (unsigned short*)(ws + alloc((size_t)32000*256*2));
  unsigned short* xg_t   = (unsigned short*)(ws + alloc((size_t)16384*768*2));
  unsigned short* xg_c   = (unsigned short*)(ws + alloc((size_t)512*768*2));
  unsigned short* xg_d   = (unsigned short*)(ws + alloc((size_t)2032*768*2));
  float*          tvec   = (float*)(ws + alloc((size_t)512*256*4));
  float*          zbuf   = (float*)(ws + alloc((size_t)512*256*4));
  float*          z2buf  = (float*)(ws + alloc((size_t)512*256*4));
  unsigned short* outsb  = (unsigned short*)(ws + alloc((size_t)2048*256*2));
  unsigned short* hbdec  = (unsigned short*)(ws + alloc((size_t)16*256*2));

  // 0) weights -> bf16 (all) + split r/zn conversion (Whh x3)
  k_cvt<<<2048, 256, 0, stream>>>(head_W, wHead,
      Wih_t, Whh_t, Wih_c, Whh_c, Wih_d, Whh_d, fuse_W,
      wWih_t, wWhh_t, wWih_c, wWhh_c, wWih_d, wWhh_d, wFuse);
  k_cvtw<<<288, 256, 0, stream>>>(Whh_t, Whh_c, Whh_d,
                                  wR_t, wR_c, wR_d, wZN_t, wZN_c, wZN_d);

  // 1) xg for ctx text GRU: rows = (b*K+k)*L + l = 16384
  k_gemm<32,32,0><<<dim3(256,6), 256, 0, stream>>>(
      emb_text, 256, nullptr, 0, 256, ctx_ids, wWih_t, bih_t, 16384, 256, xg_t, 768);

  // 1b) xg for decoder (independent): rows = b*127 + t = 2032
  k_gemm<127,128,0><<<dim3(32,6), 256, 0, stream>>>(
      tok_emb, 256, nullptr, 0, 256, tgt_ids, wWih_d, bih_d, 2032, 256, xg_d, 768);

  // 2) ctx text GRU (masked), 512 rows / 4 = 128 blocks -> tvec (f32)
  k_gru<<<128, 1024, 0, stream>>>(wR_t, wZN_t, bhh_t, xg_t, ctx_mask,
                                  nullptr, tvec, nullptr, nullptr, 32);

  // 3) fuse: z = tanh([tvec|img] @ fuse_W^T + fuse_b), 512x256
  k_gemm<1,1,1><<<dim3(8,2), 256, 0, stream>>>(
      tvec, 256, img, 512, 256, nullptr, wFuse, fuse_b, 512, 768, zbuf, 256);

  // 4) memory scan -> z2
  k_mem<<<16, 64, 0, stream>>>(zbuf, mem_init, z2buf);

  // 5) xg for ctx GRU2 from z2 (rows b*32+t = 512)
  k_gemm<1,1,0><<<dim3(8,6), 256, 0, stream>>>(
      z2buf, 256, nullptr, 0, 256, nullptr, wWih_c, bih_c, 512, 256, xg_c, 768);

  // 6) ctx GRU2: 16 rows / 4 = 4 blocks -> h0 (bf16, global rows)
  k_gru<<<4, 1024, 0, stream>>>(wR_c, wZN_c, bhh_c, xg_c, nullptr,
                                nullptr, nullptr, hbdec, nullptr, 32);

  // 7) decoder GRU: 16 rows / 4 = 4 blocks, h0 preloaded -> outs bf16
  k_gru<<<4, 1024, 0, stream>>>(wR_d, wZN_d, bhh_d, xg_d, nullptr,
                                hbdec, nullptr, nullptr, outsb, 127);

  // 8) head: logits
  k_head<<<4000, 256, 0, stream>>>(outsb, wHead, head_b, out, 2032);
}

// Round 21
// 655.687 us; speedup vs baseline: 1.2730x; 1.0230x over previous
//
#include <hip/hip_runtime.h>
#include <hip/hip_bf16.h>

typedef __attribute__((ext_vector_type(4))) float f32x4;
typedef __attribute__((ext_vector_type(8))) short short8;
typedef __attribute__((ext_vector_type(4))) unsigned int u32x4;
typedef __attribute__((ext_vector_type(4))) unsigned short u16x4;

static __device__ __forceinline__ unsigned short f2bf(float f){
  unsigned u = __builtin_bit_cast(unsigned, f);
  u += 0x7FFFu + ((u >> 16) & 1u);
  return (unsigned short)(u >> 16);
}
static __device__ __forceinline__ float bf2f(unsigned short b){
  return __builtin_bit_cast(float, ((unsigned)b) << 16);
}
// float -> OCP e4m3fn (software; one-time cvt kernel + fallback)
static __device__ __forceinline__ unsigned char f2e4m3(float x){
  unsigned u = __builtin_bit_cast(unsigned, x);
  unsigned s = (u >> 24) & 0x80u;
  float ax = __builtin_fabsf(x);
  if (ax < 0.015625f) {
    int q = (int)(ax * 512.f + 0.5f);
    return (unsigned char)(s | (unsigned)q);
  }
  if (ax > 448.f) return (unsigned char)(s | 0x7Eu);
  unsigned v = __builtin_bit_cast(unsigned, ax);
  v += 0x00080000u + ((v >> 20) & 1u);
  if (__builtin_bit_cast(float, v & 0xFFF00000u) > 448.f)
    return (unsigned char)(s | 0x7Eu);
  unsigned ee = ((v >> 23) & 0xFFu) - 127u + 7u;
  unsigned m = (v >> 20) & 7u;
  return (unsigned char)(s | (ee << 3) | m);
}
static __device__ __forceinline__ unsigned char h2fp8(float hx16){
#if __has_builtin(__builtin_amdgcn_cvt_pk_fp8_f32)
  int pk = __builtin_amdgcn_cvt_pk_fp8_f32(hx16, hx16, 0, false);
  return (unsigned char)(pk & 0xFF);
#else
  return f2e4m3(hx16);
#endif
}
static __device__ __forceinline__ f32x4 mfma16(short8 a, short8 b, f32x4 c){
  return __builtin_amdgcn_mfma_f32_16x16x32_bf16(a, b, c, 0, 0, 0);
}
static __device__ __forceinline__ f32x4 mfma8(long a, long b, f32x4 c){
  return __builtin_amdgcn_mfma_f32_16x16x32_fp8_fp8(a, b, c, 0, 0, 0);
}
static __device__ __forceinline__ float rcpf(float x){ return __builtin_amdgcn_rcpf(x); }
static __device__ __forceinline__ float sigf(float x){ return rcpf(1.f + __expf(-x)); }
static __device__ __forceinline__ float tanhfast(float x){
  float e = __expf(2.f*x);
  return (e - 1.f) * rcpf(e + 1.f);
}
// spread C-fragment: lane (l4,l15) takes component l4 of src-lane l15's vec
static __device__ __forceinline__ float spread4(f32x4 v, int l15, int l4){
  float x0 = __shfl(v[0], l15, 64);
  float x1 = __shfl(v[1], l15, 64);
  float x2 = __shfl(v[2], l15, 64);
  float x3 = __shfl(v[3], l15, 64);
  float s01 = (l4 & 1) ? x1 : x0;
  float s23 = (l4 & 1) ? x3 : x2;
  return (l4 & 2) ? s23 : s01;
}

// ---------------------------------------------------------------------------
// fp32 -> bf16 conversion: head_W + emb_text + tok_emb (big) + 4 smalls.
// Embedding tables converted ONCE so the xg GEMMs load bf16 A directly
// (halves A traffic, deletes per-load f2bf repack chains).
// ---------------------------------------------------------------------------
__global__ __launch_bounds__(256) void k_cvt(
    const float* __restrict__ sh, unsigned short* __restrict__ dh,
    const float* __restrict__ se, unsigned short* __restrict__ de,
    const float* __restrict__ st, unsigned short* __restrict__ dt,
    const float* __restrict__ s0, const float* __restrict__ s1,
    const float* __restrict__ s2, const float* __restrict__ s3,
    unsigned short* __restrict__ d0, unsigned short* __restrict__ d1,
    unsigned short* __restrict__ d2, unsigned short* __restrict__ d3)
{
  const long NH4 = 2048000;   // 8,192,000 floats / 4 (head, emb, tok each)
  const long NS4 = 49152;     // 196,608 floats / 4
  const long total = 3*NH4 + 4*NS4;
  for (long idx = (long)blockIdx.x*blockDim.x + threadIdx.x; idx < total;
       idx += (long)gridDim.x*blockDim.x) {
    const float* s; unsigned short* d; long off;
    if (idx < NH4)        { s = sh; d = dh; off = idx; }
    else if (idx < 2*NH4) { s = se; d = de; off = idx - NH4; }
    else if (idx < 3*NH4) { s = st; d = dt; off = idx - 2*NH4; }
    else {
      long r = idx - 3*NH4; int mat = (int)(r / NS4); off = r - (long)mat*NS4;
      switch (mat) {
        case 0: s=s0; d=d0; break;  case 1: s=s1; d=d1; break;
        case 2: s=s2; d=d2; break;  default: s=s3; d=d3; break;
      }
    }
    f32x4 v = ((const f32x4*)s)[off];
    u16x4 o2;
    o2[0]=f2bf(v[0]); o2[1]=f2bf(v[1]); o2[2]=f2bf(v[2]); o2[3]=f2bf(v[3]);
    ((u16x4*)d)[off] = o2;
  }
}

// ---------------------------------------------------------------------------
// Whh -> fp8 e4m3 x16 FRAG-MAJOR, ALL THREE GATES (for the all-fp8 k_gru):
//   byte off ((w*3+g)*8+kb)*512 + lane*8 ;
//   row = g*256 + w*16 + (lane&15), k0 = kb*32 + (lane>>4)*8.  192KB/mat.
// ---------------------------------------------------------------------------
__global__ __launch_bounds__(256) void k_cvtw(
    const float* __restrict__ s0, const float* __restrict__ s1,
    const float* __restrict__ s2,
    unsigned char* __restrict__ z0, unsigned char* __restrict__ z1,
    unsigned char* __restrict__ z2)
{
  int idx = blockIdx.x*256 + threadIdx.x;     // 3 mats x 24576 8B-chunks
  if (idx >= 3*24576) return;
  int mat = idx / 24576, c = idx % 24576;
  const float* s = (mat==0) ? s0 : (mat==1 ? s1 : s2);
  unsigned char* d = (mat==0) ? z0 : (mat==1 ? z1 : z2);
  int lane = c & 63;
  int rest = c >> 6;          // 0..383
  int kb = rest & 7;
  int wg = rest >> 3;         // 0..47
  int g = wg % 3, w = wg / 3;
  int row = g*256 + w*16 + (lane & 15);
  int k0  = kb*32 + (lane >> 4)*8;
  const float* sp = s + (long)row*256 + k0;
  f32x4 a = *(const f32x4*)sp;
  f32x4 b = *(const f32x4*)(sp + 4);
  unsigned char ob[8];
  ob[0]=f2e4m3(a[0]*16.f); ob[1]=f2e4m3(a[1]*16.f);
  ob[2]=f2e4m3(a[2]*16.f); ob[3]=f2e4m3(a[3]*16.f);
  ob[4]=f2e4m3(b[0]*16.f); ob[5]=f2e4m3(b[1]*16.f);
  ob[6]=f2e4m3(b[2]*16.f); ob[7]=f2e4m3(b[3]*16.f);
  unsigned lo = (unsigned)ob[0] | ((unsigned)ob[1]<<8) |
                ((unsigned)ob[2]<<16) | ((unsigned)ob[3]<<24);
  unsigned hi = (unsigned)ob[4] | ((unsigned)ob[5]<<8) |
                ((unsigned)ob[6]<<16) | ((unsigned)ob[7]<<24);
  *(unsigned*)(d + (long)c*8)     = lo;
  *(unsigned*)(d + (long)c*8 + 4) = hi;
}

// ---------------------------------------------------------------------------
// Generic MFMA GEMM: out[M][N] = gatherA[M][Ktot] @ W[N][Ktot]^T + bias
//   AT=0: fp32 A table (with optional concat tabB2); AT=1: bf16 A table.
// ---------------------------------------------------------------------------
template<int TN, int TS, int EPI, int AT>
__global__ __launch_bounds__(256) void k_gemm(
    const void* __restrict__ tabA_, int ldA,
    const float* __restrict__ tabB2, int ldB2, int K1,
    const int* __restrict__ ids,
    const unsigned short* __restrict__ W,   // [N][Ktot] bf16
    const float* __restrict__ bias,         // [N]
    int M, int Ktot,
    void* __restrict__ outp, int ldOut)
{
  const int bm = blockIdx.x, bn = blockIdx.y;
  const int tid = threadIdx.x;
  const int lane = tid & 63, w = tid >> 6;
  const int l15 = lane & 15, l4 = lane >> 4;

  const int r_g = bm*64 + w*16 + l15;
  const int r_c = (r_g < M) ? r_g : (M-1);
  long row_src;
  if (ids) { int ii = (r_c / TN) * TS + (r_c % TN); row_src = ids[ii]; }
  else row_src = r_c;

  const int kchunk = l4 * 8;
  const int ncol0 = bn*128 + l15;

  f32x4 acc[8];
  #pragma unroll
  for (int i=0;i<8;i++){ f32x4 z4 = {0.f,0.f,0.f,0.f}; acc[i]=z4; }

  const int KB = Ktot >> 5;
  for (int kb = 0; kb < KB; ++kb) {
    int k = kb*32 + kchunk;
    short8 afr;
    if (AT == 1) {
      afr = *(const short8*)((const unsigned short*)tabA_ + row_src*(long)ldA + k);
    } else {
      const float* ap;
      if (tabB2 && k >= K1) ap = tabB2 + row_src*(long)ldB2 + (k - K1);
      else                  ap = (const float*)tabA_ + row_src*(long)ldA + k;
      f32x4 a0 = *(const f32x4*)ap;
      f32x4 a1 = *(const f32x4*)(ap + 4);
      afr[0]=(short)f2bf(a0[0]); afr[1]=(short)f2bf(a0[1]);
      afr[2]=(short)f2bf(a0[2]); afr[3]=(short)f2bf(a0[3]);
      afr[4]=(short)f2bf(a1[0]); afr[5]=(short)f2bf(a1[1]);
      afr[6]=(short)f2bf(a1[2]); afr[7]=(short)f2bf(a1[3]);
    }
    #pragma unroll
    for (int ct=0; ct<8; ++ct) {
      int n = ncol0 + ct*16;
      short8 bfr = *(const short8*)(W + (long)n*Ktot + k);
      acc[ct] = mfma16(afr, bfr, acc[ct]);
    }
  }

  #pragma unroll
  for (int ct=0; ct<8; ++ct) {
    int n = ncol0 + ct*16;
    float bv = bias[n];
    #pragma unroll
    for (int q=0; q<4; ++q) {
      int rr = bm*64 + w*16 + l4*4 + q;
      if (rr < M) {
        float v = acc[ct][q] + bv;
        if (EPI == 1) ((float*)outp)[(long)rr*ldOut + n] = tanhfast(v);
        else ((unsigned short*)outp)[(long)rr*ldOut + n] = f2bf(v);
      }
    }
  }
}

// ---------------------------------------------------------------------------
// GRU recurrence, ROW-SPLIT (4 rows/block) + SHUFFLE-SPREAD GATES + ALL-FP8.
//   R20 (194us decoder): MFMA floor ~1860cy/step, LDS issue ~2300cy/step
//   (b128 bf16 A + b64 fp8 A per wave per kb) were co-bottlenecks.
//   This round: single fp8 A-path for ALL gates -> 8 x b64/wave/step
//   (~768cy), weights = 24 longs = 48 VGPR fp8 frag-major. LDS = 2.4KB.
//   Accuracy: r-gate now sees fp8 h (was bf16); contractive recurrence
//   bounds absmax ~1e-3 (< 2.3e-3 threshold).
// ---------------------------------------------------------------------------
__global__ __launch_bounds__(1024, 1) void k_gru(
    const unsigned char*  __restrict__ WF8,  // fp8 all-gate frag-major (k_cvtw)
    const float* __restrict__ bhh,           // [768]
    const unsigned short* __restrict__ xg,   // [(grow*T+t)][768] bf16 (bih inc.)
    const int* __restrict__ mask,            // [(grow*T+t)] or null
    const unsigned short* __restrict__ h0bf, // [16][256] bf16 GLOBAL rows, or null
    float* __restrict__ hNf,                 // [grow][256] f32 or null
    unsigned short* __restrict__ hNbf,       // [16][256] bf16 GLOBAL rows, or null
    unsigned short* __restrict__ outs,       // [(grow*T+t)][256] bf16 or null
    int T)
{
  __shared__ unsigned char h8z[9*264];       // fp8 h(x16): rows0-3=p0,4-7=p1,8=zero

  const int tid = threadIdx.x;
  const int w = tid >> 6, lane = tid & 63;
  const int l15 = lane & 15, l4 = lane >> 4;
  const int rowbase = blockIdx.x * 4;
  const int u = w*16 + l15;                  // this lane's unit
  const int gr = l4;                         // this lane's gate row (0..3)

  // ---- weights: all three gates fp8 -> 24 longs (48 VGPR) ----
  long Bf8[3][8];
  #pragma unroll
  for (int g=0; g<3; ++g)
    #pragma unroll
    for (int kb=0; kb<8; ++kb)
      Bf8[g][kb] = *(const long*)(WF8 + ((long)((w*3+g)*8+kb)*512) + lane*8);

  const float b_r = bhh[u], b_z = bhh[256+u], b_n = bhh[512+u];

  // A-read offsets (parity-selected; tile rows >=4 alias zero-row 8)
  const int arow0 = (l15 < 4) ? l15     : 8;
  const int arow1 = (l15 < 4) ? 4 + l15 : 8;
  const int h8O0 = arow0*264 + l4*8;
  const int h8O1 = arow1*264 + l4*8;

  // ---- init: zero row 8; lane owns (row gr, unit u); exact f32 h ----
  if (tid < 264) h8z[8*264 + tid] = 0;
  float h = h0bf ? bf2f(h0bf[(rowbase+gr)*256 + u]) : 0.f;
  h8z[gr*264 + u] = h2fp8(h * 16.f);
  __syncthreads();

  const float inv256 = 0.00390625f;

  for (int t=0; t<T; ++t) {
    const int p = t & 1;

    // ---- xg prefetch: one triple per lane (hides under MFMA) ----
    const long xrow = (long)(rowbase + gr)*T + t;
    const unsigned short* xp = xg + xrow*768;
    const unsigned short xr_ = xp[u];
    const unsigned short xz_ = xp[256+u];
    const unsigned short xn_ = xp[512+u];
    const int mok = mask ? mask[xrow] : 1;

    // ---- MFMA: 16 units x 3 gates; A is one b64 fp8 read per kb ----
    const int h8O = p ? h8O1 : h8O0;
    f32x4 aR={0.f,0.f,0.f,0.f}, aZ={0.f,0.f,0.f,0.f}, aN={0.f,0.f,0.f,0.f};
    #pragma unroll
    for (int kb=0; kb<8; ++kb) {
      long a8 = *(const long*)&h8z[h8O + kb*32];
      aR = mfma8(a8, Bf8[0][kb], aR);
      aZ = mfma8(a8, Bf8[1][kb], aZ);
      aN = mfma8(a8, Bf8[2][kb], aN);
    }

    // ---- spread C rows across the wave; ONE gate triple per lane ----
    float gR = spread4(aR, l15, l4) * inv256;
    float gZ = spread4(aZ, l15, l4) * inv256;
    float gN = spread4(aN, l15, l4) * inv256;

    float rr = sigf(bf2f(xr_) + gR + b_r);
    float zz = sigf(bf2f(xz_) + gZ + b_z);
    float nn = tanhfast(bf2f(xn_) + rr*(gN + b_n));
    float hv = nn + zz*(h - nn);
    if (!mok) hv = h;
    h = hv;
    const int wrow = (p^1)*4 + gr;
    h8z[wrow*264 + u] = h2fp8(hv * 16.f);
    if (outs) outs[xrow*256 + u] = f2bf(hv);
    __syncthreads();
  }

  if (hNf)  hNf[(long)(rowbase+gr)*256 + u] = h;
  if (hNbf) hNbf[(rowbase+gr)*256 + u] = f2bf(h);
}

// ---------------------------------------------------------------------------
// Memory scan: per batch b (block, 1 wave): 32 steps of attention-write memory.
// ---------------------------------------------------------------------------
__global__ __launch_bounds__(64) void k_mem(
    const float* __restrict__ z,         // [512][256] rows b*32+t
    const float* __restrict__ mem_init,  // [16][256]
    float* __restrict__ z2)              // [512][256]
{
  const int b = blockIdx.x;
  const int lane = threadIdx.x;
  float mem[16][4];
  #pragma unroll
  for (int m=0; m<16; ++m) {
    f32x4 v = *(const f32x4*)(mem_init + m*256 + lane*4);
    mem[m][0]=v[0]; mem[m][1]=v[1]; mem[m][2]=v[2]; mem[m][3]=v[3];
  }
  for (int t=0; t<32; ++t) {
    f32x4 q = *(const f32x4*)(z + ((long)b*32 + t)*256 + lane*4);
    float s[16];
    #pragma unroll
    for (int m=0; m<16; ++m)
      s[m] = mem[m][0]*q[0] + mem[m][1]*q[1] + mem[m][2]*q[2] + mem[m][3]*q[3];
    #pragma unroll
    for (int st=1; st<64; st<<=1) {
      #pragma unroll
      for (int m=0; m<16; ++m) s[m] += __shfl_xor(s[m], st, 64);
    }
    float mx = -1e30f;
    #pragma unroll
    for (int m=0; m<16; ++m) { s[m] *= 0.0625f; mx = fmaxf(mx, s[m]); }
    float sum = 0.f;
    #pragma unroll
    for (int m=0; m<16; ++m) { s[m] = __expf(s[m]-mx); sum += s[m]; }
    float inv = rcpf(sum);
    f32x4 ro = {0.f,0.f,0.f,0.f};
    #pragma unroll
    for (int m=0; m<16; ++m) {
      float wm = s[m]*inv;
      #pragma unroll
      for (int c=0; c<4; ++c) {
        ro[c] += wm * mem[m][c];
        mem[m][c] += wm * (q[c] - mem[m][c]);
      }
    }
    f32x4 o = q + ro;
    *(f32x4*)(z2 + ((long)b*32 + t)*256 + lane*4) = o;
  }
}

// ---------------------------------------------------------------------------
// Head GEMM: out[2032][32000] = A[2032][256]bf16 @ Bw[32000][256]^T + bias
// ---------------------------------------------------------------------------
__global__ __launch_bounds__(256) void k_head(
    const unsigned short* __restrict__ A,    // [2048][256] bf16 (padded)
    const unsigned short* __restrict__ Bw,   // [32000][256] bf16
    const float* __restrict__ bias,          // [32000]
    float* __restrict__ out,                 // [2032][32000]
    int M)
{
  __shared__ unsigned short Bs[32768];       // 64 KB
  const int bid = blockIdx.x;
  const int mt = bid % 16, nt = bid / 16;
  const int tid = threadIdx.x;
  const int lane = tid & 63, w = tid >> 6;
  const int l15 = lane & 15, l4 = lane >> 4;

  const long nbase = (long)nt * 128;
  #pragma unroll
  for (int it=0; it<16; ++it) {
    int idx = it*256 + tid;
    int rr = idx >> 5;
    int ch = idx & 31;
    int sch = ch ^ (rr & 7);
    u32x4 v = *(const u32x4*)(Bw + (nbase+rr)*256 + sch*8);
    *(u32x4*)&Bs[(long)idx*8] = v;
  }
  __syncthreads();

  const int m0 = mt*128 + w*32;
  const int arow0 = m0 + l15, arow1 = arow0 + 16;
  const int kc = l4 * 8;

  f32x4 acc[2][8];
  #pragma unroll
  for (int rt=0; rt<2; ++rt)
    #pragma unroll
    for (int ct=0; ct<8; ++ct){ f32x4 z4={0.f,0.f,0.f,0.f}; acc[rt][ct]=z4; }

  #pragma unroll
  for (int kb=0; kb<8; ++kb) {
    short8 a0 = *(const short8*)(A + (long)arow0*256 + kb*32 + kc);
    short8 a1 = *(const short8*)(A + (long)arow1*256 + kb*32 + kc);
    int c = kb*4 + l4;
    #pragma unroll
    for (int ct=0; ct<8; ++ct) {
      int n_local = ct*16 + l15;
      int sc = c ^ (n_local & 7);
      short8 bf = *(const short8*)&Bs[((long)n_local*32 + sc)*8];
      acc[0][ct] = mfma16(a0, bf, acc[0][ct]);
      acc[1][ct] = mfma16(a1, bf, acc[1][ct]);
    }
  }

  #pragma unroll
  for (int ct=0; ct<8; ++ct) {
    int n_g = nt*128 + ct*16 + l15;
    float bv = bias[n_g];
    #pragma unroll
    for (int rt=0; rt<2; ++rt) {
      #pragma unroll
      for (int q=0; q<4; ++q) {
        int r_g = m0 + rt*16 + l4*4 + q;
        if (r_g < M) out[(long)r_g*32000 + n_g] = acc[rt][ct][q] + bv;
      }
    }
  }
}

// ---------------------------------------------------------------------------
extern "C" void kernel_launch(void* const* d_in, const int* in_sizes, int n_in,
                              void* d_out, int out_size, void* d_ws, size_t ws_size,
                              hipStream_t stream)
{
  (void)in_sizes; (void)n_in; (void)out_size; (void)ws_size;
  const int*   ctx_ids  = (const int*)  d_in[0];
  const int*   ctx_mask = (const int*)  d_in[1];
  const float* img      = (const float*)d_in[2];
  const int*   tgt_ids  = (const int*)  d_in[3];
  const float* emb_text = (const float*)d_in[4];
  const float* Wih_t    = (const float*)d_in[5];
  const float* Whh_t    = (const float*)d_in[6];
  const float* bih_t    = (const float*)d_in[7];
  const float* bhh_t    = (const float*)d_in[8];
  const float* fuse_W   = (const float*)d_in[9];
  const float* fuse_b   = (const float*)d_in[10];
  const float* mem_init = (const float*)d_in[11];
  const float* Wih_c    = (const float*)d_in[12];
  const float* Whh_c    = (const float*)d_in[13];
  const float* bih_c    = (const float*)d_in[14];
  const float* bhh_c    = (const float*)d_in[15];
  const float* tok_emb  = (const float*)d_in[16];
  const float* Wih_d    = (const float*)d_in[17];
  const float* Whh_d    = (const float*)d_in[18];
  const float* bih_d    = (const float*)d_in[19];
  const float* bhh_d    = (const float*)d_in[20];
  const float* head_W   = (const float*)d_in[21];
  const float* head_b   = (const float*)d_in[22];
  float* out = (float*)d_out;
  char* ws = (char*)d_ws;

  size_t o = 0;
  auto alloc = [&](size_t bytes){ size_t r = o; o += (bytes + 255) & ~(size_t)255; return r; };
  unsigned short* wWih_t = (unsigned short*)(ws + alloc(768*256*2));
  unsigned short* wWih_c = (unsigned short*)(ws + alloc(768*256*2));
  unsigned short* wWih_d = (unsigned short*)(ws + alloc(768*256*2));
  unsigned short* wFuse  = (unsigned short*)(ws + alloc(256*768*2));
  unsigned char*  wF8_t  = (unsigned char*)(ws + alloc(196608));
  unsigned char*  wF8_c  = (unsigned char*)(ws + alloc(196608));
  unsigned char*  wF8_d  = (unsigned char*)(ws + alloc(196608));
  unsigned short* wHead  = (unsigned short*)(ws + alloc((size_t)32000*256*2));
  unsigned short* ebf    = (unsigned short*)(ws + alloc((size_t)32000*256*2));
  unsigned short* tbf    = (unsigned short*)(ws + alloc((size_t)32000*256*2));
  unsigned short* xg_t   = (unsigned short*)(ws + alloc((size_t)16384*768*2));
  unsigned short* xg_c   = (unsigned short*)(ws + alloc((size_t)512*768*2));
  unsigned short* xg_d   = (unsigned short*)(ws + alloc((size_t)2032*768*2));
  float*          tvec   = (float*)(ws + alloc((size_t)512*256*4));
  float*          zbuf   = (float*)(ws + alloc((size_t)512*256*4));
  float*          z2buf  = (float*)(ws + alloc((size_t)512*256*4));
  unsigned short* outsb  = (unsigned short*)(ws + alloc((size_t)2048*256*2));
  unsigned short* hbdec  = (unsigned short*)(ws + alloc((size_t)16*256*2));

  // 0) weights+tables -> bf16; Whh x3 -> fp8 frag-major
  k_cvt<<<4096, 256, 0, stream>>>(head_W, wHead, emb_text, ebf, tok_emb, tbf,
      Wih_t, Wih_c, Wih_d, fuse_W,
      wWih_t, wWih_c, wWih_d, wFuse);
  k_cvtw<<<288, 256, 0, stream>>>(Whh_t, Whh_c, Whh_d, wF8_t, wF8_c, wF8_d);

  // 1) xg for ctx text GRU (bf16 A table): rows = (b*K+k)*L + l = 16384
  k_gemm<32,32,0,1><<<dim3(256,6), 256, 0, stream>>>(
      ebf, 256, nullptr, 0, 256, ctx_ids, wWih_t, bih_t, 16384, 256, xg_t, 768);

  // 1b) xg for decoder (bf16 A table): rows = b*127 + t = 2032
  k_gemm<127,128,0,1><<<dim3(32,6), 256, 0, stream>>>(
      tbf, 256, nullptr, 0, 256, tgt_ids, wWih_d, bih_d, 2032, 256, xg_d, 768);

  // 2) ctx text GRU (masked), 512 rows / 4 = 128 blocks -> tvec (f32)
  k_gru<<<128, 1024, 0, stream>>>(wF8_t, bhh_t, xg_t, ctx_mask,
                                  nullptr, tvec, nullptr, nullptr, 32);

  // 3) fuse: z = tanh([tvec|img] @ fuse_W^T + fuse_b), 512x256
  k_gemm<1,1,1,0><<<dim3(8,2), 256, 0, stream>>>(
      tvec, 256, img, 512, 256, nullptr, wFuse, fuse_b, 512, 768, zbuf, 256);

  // 4) memory scan -> z2
  k_mem<<<16, 64, 0, stream>>>(zbuf, mem_init, z2buf);

  // 5) xg for ctx GRU2 from z2 (rows b*32+t = 512)
  k_gemm<1,1,0,0><<<dim3(8,6), 256, 0, stream>>>(
      z2buf, 256, nullptr, 0, 256, nullptr, wWih_c, bih_c, 512, 256, xg_c, 768);

  // 6) ctx GRU2: 16 rows / 4 = 4 blocks -> h0 (bf16, global rows)
  k_gru<<<4, 1024, 0, stream>>>(wF8_c, bhh_c, xg_c, nullptr,
                                nullptr, nullptr, hbdec, nullptr, 32);

  // 7) decoder GRU: 16 rows / 4 = 4 blocks, h0 preloaded -> outs bf16
  k_gru<<<4, 1024, 0, stream>>>(wF8_d, bhh_d, xg_d, nullptr,
                                hbdec, nullptr, nullptr, outsb, 127);

  // 8) head: logits
  k_head<<<4000, 256, 0, stream>>>(outsb, wHead, head_b, out, 2032);
}